// Round 1
// baseline (199.666 us; speedup 1.0000x reference)
//
#include <hip/hip_runtime.h>
#include <math.h>
#include <stdint.h>

#define NS   16
#define HWSZ 409600
#define EPB  4096   // elements per block
#define BPS  100    // blocks per sample (BPS*EPB == HWSZ)
#define NB1  2048
#define NB2  2048
#define NB3  1024

__device__ __forceinline__ unsigned int fkey(float f) {
    unsigned int u = __float_as_uint(f);
    return (u & 0x80000000u) ? ~u : (u | 0x80000000u);
}
__device__ __forceinline__ float fkey_inv(unsigned int u) {
    unsigned int b = (u & 0x80000000u) ? (u & 0x7FFFFFFFu) : ~u;
    return __uint_as_float(b);
}

// ---------------- pass 1: counts + top-11-bit histogram of negative keys ----
__global__ void k_hist1(const float* __restrict__ outputs, const float* __restrict__ labels,
                        const float* __restrict__ tmask,
                        int* __restrict__ hist1, int* __restrict__ cnt_pos, int* __restrict__ cnt_neg) {
    __shared__ int lh[NB1];
    __shared__ int lpos, lneg;
    const int t = threadIdx.x;
    const int n = blockIdx.y;
    for (int i = t; i < NB1; i += 256) lh[i] = 0;
    if (t == 0) { lpos = 0; lneg = 0; }
    __syncthreads();
    const float4* P = (const float4*)(outputs + (size_t)n * 2 * HWSZ);
    const float4* G = (const float4*)(labels  + (size_t)n * 2 * HWSZ);
    const float4* T = (const float4*)(tmask   + (size_t)n * HWSZ);
    const int base4 = blockIdx.x * (EPB / 4);
    int mypos = 0, myneg = 0;
    for (int j = 0; j < 4; ++j) {
        int i4 = base4 + j * 256 + t;
        float4 p = P[i4], g = G[i4], m = T[i4];
        const float* pp = (const float*)&p;
        const float* gg = (const float*)&g;
        const float* mm = (const float*)&m;
#pragma unroll
        for (int e = 0; e < 4; ++e) {
            if (mm[e] > 0.5f) {
                if (gg[e] > 0.5f) mypos++;
                else { myneg++; atomicAdd(&lh[fkey(pp[e]) >> 21], 1); }
            }
        }
    }
    if (mypos) atomicAdd(&lpos, mypos);
    if (myneg) atomicAdd(&lneg, myneg);
    __syncthreads();
    int* gh = hist1 + n * NB1;
    for (int i = t; i < NB1; i += 256) if (lh[i]) atomicAdd(&gh[i], lh[i]);
    if (t == 0) { if (lpos) atomicAdd(&cnt_pos[n], lpos); if (lneg) atomicAdd(&cnt_neg[n], lneg); }
}

// ---------------- refine histograms (pass 2: next 11 bits, pass 3: last 10) -
template <int PASS>
__global__ void k_histN(const float* __restrict__ outputs, const float* __restrict__ labels,
                        const float* __restrict__ tmask, const int* __restrict__ mode,
                        const int* __restrict__ b1, const int* __restrict__ b2,
                        int* __restrict__ hist) {
    const int n = blockIdx.y;
    if (mode[n] != 0) return;
    constexpr int NB = (PASS == 2) ? NB2 : NB3;
    __shared__ int lh[NB];
    const int t = threadIdx.x;
    for (int i = t; i < NB; i += 256) lh[i] = 0;
    __syncthreads();
    const unsigned pref = (PASS == 2) ? (unsigned)b1[n]
                                      : (((unsigned)b1[n] << 11) | (unsigned)b2[n]);
    const float4* P = (const float4*)(outputs + (size_t)n * 2 * HWSZ);
    const float4* G = (const float4*)(labels  + (size_t)n * 2 * HWSZ);
    const float4* T = (const float4*)(tmask   + (size_t)n * HWSZ);
    const int base4 = blockIdx.x * (EPB / 4);
    for (int j = 0; j < 4; ++j) {
        int i4 = base4 + j * 256 + t;
        float4 p = P[i4], g = G[i4], m = T[i4];
        const float* pp = (const float*)&p;
        const float* gg = (const float*)&g;
        const float* mm = (const float*)&m;
#pragma unroll
        for (int e = 0; e < 4; ++e) {
            if (mm[e] > 0.5f && gg[e] <= 0.5f) {
                unsigned u = fkey(pp[e]);
                if (PASS == 2) {
                    if ((u >> 21) == pref) atomicAdd(&lh[(u >> 10) & 0x7FFu], 1);
                } else {
                    if ((u >> 10) == pref) atomicAdd(&lh[u & 0x3FFu], 1);
                }
            }
        }
    }
    __syncthreads();
    int* gh = hist + n * NB;
    for (int i = t; i < NB; i += 256) if (lh[i]) atomicAdd(&gh[i], lh[i]);
}

// Wave-parallel descending k-th-largest bin search. Returns true on the (one)
// lane whose chunk contains the crossing; that lane gets bin+rank.
__device__ __forceinline__ bool wave_find(const int* __restrict__ h, int nbins, int k,
                                          int* bin_out, int* rank_out) {
    const int lane = threadIdx.x;
    const int CH = nbins >> 6;
    const int topStart = nbins - 1 - lane * CH;
    int s = 0;
    for (int b = 0; b < CH; ++b) s += h[topStart - b];
    int incl = s;
    for (int off = 1; off < 64; off <<= 1) {
        int v = __shfl_up(incl, off, 64);
        if (lane >= off) incl += v;
    }
    int before = incl - s;
    if (before < k && k <= incl) {
        int c = before;
        for (int b = 0; b < CH; ++b) {
            int hb = h[topStart - b];
            c += hb;
            if (c >= k) { *bin_out = topStart - b; *rank_out = k - (c - hb); return true; }
        }
    }
    return false;
}

__global__ void k_sel1(const int* __restrict__ cnt_pos, const int* __restrict__ cnt_neg,
                       const int* __restrict__ hist1,
                       int* __restrict__ mode, int* __restrict__ b1, int* __restrict__ k1) {
    const int n = blockIdx.x;
    const int pos = cnt_pos[n], neg = cnt_neg[n];
    int k = pos * 3; if (k > neg) k = neg;
    if (pos == 0) { if (threadIdx.x == 0) mode[n] = 2; return; }
    if (k == 0)   { if (threadIdx.x == 0) mode[n] = 1; return; }
    if (threadIdx.x == 0) mode[n] = 0;
    int bin, rank;
    if (wave_find(hist1 + n * NB1, NB1, k, &bin, &rank)) { b1[n] = bin; k1[n] = rank; }
}

__global__ void k_sel2(const int* __restrict__ mode, const int* __restrict__ hist2,
                       const int* __restrict__ k1, int* __restrict__ b2, int* __restrict__ k2) {
    const int n = blockIdx.x;
    if (mode[n] != 0) return;
    int bin, rank;
    if (wave_find(hist2 + n * NB2, NB2, k1[n], &bin, &rank)) { b2[n] = bin; k2[n] = rank; }
}

__global__ void k_sel3(const int* __restrict__ mode, const int* __restrict__ hist3,
                       const int* __restrict__ k2, const int* __restrict__ b1,
                       const int* __restrict__ b2, float* __restrict__ thr) {
    const int n = blockIdx.x;
    if (mode[n] != 0) return;
    const unsigned v1 = (unsigned)b1[n], v2 = (unsigned)b2[n];
    int bin, rank;
    if (wave_find(hist3 + n * NB3, NB3, k2[n], &bin, &rank)) {
        unsigned key = (v1 << 21) | (v2 << 10) | (unsigned)bin;
        thr[n] = fkey_inv(key);
    }
}

// ---------------- fused loss pass ------------------------------------------
__global__ void k_loss(const float* __restrict__ outputs, const float* __restrict__ labels,
                       const float* __restrict__ tmask, const float* __restrict__ gd,
                       const int* __restrict__ mode, const float* __restrict__ thr,
                       double* __restrict__ acc) {
    const int t = threadIdx.x;
    const int n = blockIdx.y;
    const int md = mode[n];
    const float th = thr[n];
    const float4* P  = (const float4*)(outputs + (size_t)n * 2 * HWSZ);
    const float4* Th = (const float4*)(outputs + (size_t)n * 2 * HWSZ + HWSZ);
    const float4* G  = (const float4*)(labels  + (size_t)n * 2 * HWSZ);
    const float4* Gt = (const float4*)(labels  + (size_t)n * 2 * HWSZ + HWSZ);
    const float4* T  = (const float4*)(tmask   + (size_t)n * HWSZ);
    const float4* D  = (const float4*)(gd      + (size_t)n * HWSZ);
    const int base4 = blockIdx.x * (EPB / 4);
    float s1 = 0.f, s2 = 0.f, ssel = 0.f, s3 = 0.f, s4 = 0.f;
    for (int j = 0; j < 4; ++j) {
        int i4 = base4 + j * 256 + t;
        float4 p = P[i4], tv4 = Th[i4], g = G[i4], gt4 = Gt[i4], m = T[i4], d = D[i4];
        const float* pp = (const float*)&p;  const float* tt4 = (const float*)&tv4;
        const float* gg = (const float*)&g;  const float* gt = (const float*)&gt4;
        const float* mm = (const float*)&m;  const float* dd = (const float*)&d;
#pragma unroll
        for (int e = 0; e < 4; ++e) {
            float pv = pp[e], tv = tt4[e], gv = gg[e], gtv = gt[e], mv = mm[e], dv = dd[e];
            bool tmk  = mv > 0.5f;
            bool posB = (gv > 0.5f) && tmk;
            bool negB = (gv <= 0.5f) && tmk;
            float sel;
            if (md == 2)      sel = tmk ? 1.0f : 0.0f;
            else if (md == 1) sel = posB ? 1.0f : 0.0f;
            else              sel = (posB || (negB && pv >= th)) ? 1.0f : 0.0f;
            float tcls = (gv > 0.5f) ? 1.0f : 0.0f;
            float pc = fminf(fmaxf(pv, 1e-7f), 1.0f - 1e-7f);
            float bce1 = -(tcls * logf(pc) + (1.0f - tcls) * log1pf(-pc));
            float x = 50.0f * (pv - tv);
            float bm = 1.0f / (1.0f + expf(-x));
            float p2 = fminf(fmaxf(bm, 1e-7f), 1.0f - 1e-7f);
            float bce2 = -(tcls * logf(p2) + (1.0f - tcls) * log1pf(-p2));
            s1 += bce1 * sel;
            s2 += bce2 * sel;
            ssel += sel;
            s3 += fabsf(tv - gtv) * dv;
            s4 += dv;
        }
    }
    // block reduce 5 accumulators in double, then one atomic each
    double v[5] = {(double)s1, (double)s2, (double)ssel, (double)s3, (double)s4};
    for (int off = 32; off > 0; off >>= 1)
#pragma unroll
        for (int i = 0; i < 5; ++i) v[i] += __shfl_down(v[i], off, 64);
    __shared__ double red[4][5];
    const int lane = t & 63, wid = t >> 6;
    if (lane == 0)
#pragma unroll
        for (int i = 0; i < 5; ++i) red[wid][i] = v[i];
    __syncthreads();
    if (t == 0) {
#pragma unroll
        for (int i = 0; i < 5; ++i) {
            double f = red[0][i] + red[1][i] + red[2][i] + red[3][i];
            atomicAdd(&acc[i], f);
        }
    }
}

__global__ void k_fin(const double* __restrict__ acc, float* __restrict__ out) {
    if (threadIdx.x != 0 || blockIdx.x != 0) return;
    double msum = acc[2];
    double lp = (msum > 0.0) ? acc[0] / msum : 0.0;
    double lb = (msum > 0.0) ? acc[1] / msum : 0.0;
    double lt = acc[3] / (acc[4] + 1e-6);
    out[0] = (float)(lp + lb + 10.0 * lt);
    out[1] = (float)lp;
    out[2] = (float)lb;
    out[3] = (float)lt;
}

extern "C" void kernel_launch(void* const* d_in, const int* in_sizes, int n_in,
                              void* d_out, int out_size, void* d_ws, size_t ws_size,
                              hipStream_t stream) {
    const float* outputs = (const float*)d_in[0];
    const float* labels  = (const float*)d_in[1];
    const float* tmask   = (const float*)d_in[2];
    const float* gd      = (const float*)d_in[3];
    float* out = (float*)d_out;

    char* ws = (char*)d_ws;
    int* hist1   = (int*)ws;                  // NS*NB1
    int* hist2   = hist1 + NS * NB1;          // NS*NB2
    int* hist3   = hist2 + NS * NB2;          // NS*NB3
    int* cnt_pos = hist3 + NS * NB3;          // NS
    int* cnt_neg = cnt_pos + NS;              // NS
    int* mode    = cnt_neg + NS;              // NS
    int* b1      = mode + NS;                 // NS
    int* k1      = b1 + NS;                   // NS
    int* b2      = k1 + NS;                   // NS
    int* k2      = b2 + NS;                   // NS
    float* thr   = (float*)(k2 + NS);         // NS
    double* acc  = (double*)(((uintptr_t)(thr + NS) + 15) & ~(uintptr_t)15); // 5 doubles
    size_t total = (size_t)((char*)(acc + 5) - ws);

    hipMemsetAsync(d_ws, 0, total, stream);

    dim3 grid(BPS, NS), blk(256);
    k_hist1<<<grid, blk, 0, stream>>>(outputs, labels, tmask, hist1, cnt_pos, cnt_neg);
    k_sel1<<<NS, 64, 0, stream>>>(cnt_pos, cnt_neg, hist1, mode, b1, k1);
    k_histN<2><<<grid, blk, 0, stream>>>(outputs, labels, tmask, mode, b1, b2, hist2);
    k_sel2<<<NS, 64, 0, stream>>>(mode, hist2, k1, b2, k2);
    k_histN<3><<<grid, blk, 0, stream>>>(outputs, labels, tmask, mode, b1, b2, hist3);
    k_sel3<<<NS, 64, 0, stream>>>(mode, hist3, k2, b1, b2, thr);
    k_loss<<<grid, blk, 0, stream>>>(outputs, labels, tmask, gd, mode, thr, acc);
    k_fin<<<1, 64, 0, stream>>>(acc, out);
}

// Round 2
// 119.577 us; speedup vs baseline: 1.6698x; 1.6698x over previous
//
#include <hip/hip_runtime.h>
#include <math.h>
#include <stdint.h>

#define NS   16
#define HWSZ 409600
#define EPB  4096   // elements per block in scan kernels
#define BPS  100    // blocks per sample (BPS*EPB == HWSZ)
#define NB1  2048
#define CAP  4096
#define BCE_MAX 16.118095651f   // -log(1e-7)

__device__ __forceinline__ unsigned fkey(float f) {
    unsigned u = __float_as_uint(f);
    if (u == 0x80000000u) u = 0u;                 // canonicalize -0
    return (u & 0x80000000u) ? ~u : (u | 0x80000000u);
}

__device__ __forceinline__ float fast_sp(float y) {   // log(1+e^y)
    float t = __expf(-fabsf(y));
    float sp = __logf(1.0f + t);
    return (y > 0.0f) ? y + sp : sp;
}

// bce1: plain BCE on p; bce2: BCE on sigmoid(50(p-t)); both with 1e-7 clipping
__device__ __forceinline__ void bce_pair(float pv, float tv, bool tcls, float& o1, float& o2) {
    float pc = fminf(fmaxf(pv, 1e-7f), 1.0f - 1e-7f);
    o1 = tcls ? -__logf(pc) : -__logf(1.0f - pc);
    float x = 50.0f * (pv - tv);
    float y = tcls ? -x : x;
    o2 = fminf(fast_sp(y), BCE_MAX);
}

// Wave-parallel descending k-th-largest bin search over a histogram.
__device__ __forceinline__ bool wave_find(const int* __restrict__ h, int nbins, int k,
                                          int* bin_out, int* rank_out) {
    const int lane = threadIdx.x & 63;
    const int CH = nbins >> 6;
    const int topStart = nbins - 1 - lane * CH;
    int s = 0;
    for (int b = 0; b < CH; ++b) s += h[topStart - b];
    int incl = s;
    for (int off = 1; off < 64; off <<= 1) {
        int v = __shfl_up(incl, off, 64);
        if (lane >= off) incl += v;
    }
    int before = incl - s;
    if (before < k && k <= incl) {
        int c = before;
        for (int b = 0; b < CH; ++b) {
            int hb = h[topStart - b];
            c += hb;
            if (c >= k) { *bin_out = topStart - b; *rank_out = k - (c - hb); return true; }
        }
    }
    return false;
}

// ---------------- fat pass: everything computable without the threshold -----
__global__ void k_scan1(const float* __restrict__ outputs, const float* __restrict__ labels,
                        const float* __restrict__ tmask, const float* __restrict__ gd,
                        int* __restrict__ hist1, int* __restrict__ cnt_pos, int* __restrict__ cnt_neg,
                        double* __restrict__ psum, double* __restrict__ acc) {
    __shared__ int lh[NB1];
    __shared__ double rd[4][6];
    __shared__ int ri[4][2];
    const int t = threadIdx.x, n = blockIdx.y;
    for (int i = t; i < NB1; i += 256) lh[i] = 0;
    __syncthreads();
    const float4* P  = (const float4*)(outputs + (size_t)n * 2 * HWSZ);
    const float4* Th = (const float4*)(outputs + (size_t)n * 2 * HWSZ + HWSZ);
    const float4* G  = (const float4*)(labels  + (size_t)n * 2 * HWSZ);
    const float4* Gt = (const float4*)(labels  + (size_t)n * 2 * HWSZ + HWSZ);
    const float4* T  = (const float4*)(tmask   + (size_t)n * HWSZ);
    const float4* D  = (const float4*)(gd      + (size_t)n * HWSZ);
    const int base4 = blockIdx.x * (EPB / 4);
    float p1 = 0.f, p2 = 0.f, n1 = 0.f, n2 = 0.f, s3 = 0.f, s4 = 0.f;
    int cp = 0, cn = 0;
    for (int j = 0; j < 4; ++j) {
        int i4 = base4 + j * 256 + t;
        float4 p = P[i4], th4 = Th[i4], g = G[i4], gt4 = Gt[i4], m = T[i4], d = D[i4];
        const float* pp = (const float*)&p;   const float* tt = (const float*)&th4;
        const float* gg = (const float*)&g;   const float* gt = (const float*)&gt4;
        const float* mm = (const float*)&m;   const float* dd = (const float*)&d;
#pragma unroll
        for (int e = 0; e < 4; ++e) {
            float pv = pp[e], tv = tt[e], gv = gg[e], gtv = gt[e], mv = mm[e], dv = dd[e];
            s3 += fabsf(tv - gtv) * dv;
            s4 += dv;
            if (mv > 0.5f) {
                bool tcls = gv > 0.5f;
                float b1v, b2v; bce_pair(pv, tv, tcls, b1v, b2v);
                if (tcls) { p1 += b1v; p2 += b2v; cp++; }
                else      { n1 += b1v; n2 += b2v; cn++;
                            atomicAdd(&lh[fkey(pv) >> 21], 1); }
            }
        }
    }
    double v[6] = {(double)p1, (double)p2, (double)n1, (double)n2, (double)s3, (double)s4};
    for (int off = 32; off; off >>= 1) {
#pragma unroll
        for (int i = 0; i < 6; ++i) v[i] += __shfl_down(v[i], off, 64);
        cp += __shfl_down(cp, off, 64);
        cn += __shfl_down(cn, off, 64);
    }
    const int lane = t & 63, wid = t >> 6;
    if (!lane) {
#pragma unroll
        for (int i = 0; i < 6; ++i) rd[wid][i] = v[i];
        ri[wid][0] = cp; ri[wid][1] = cn;
    }
    __syncthreads();
    if (!t) {
#pragma unroll
        for (int i = 0; i < 6; ++i) {
            double s = rd[0][i] + rd[1][i] + rd[2][i] + rd[3][i];
            if (i < 4) atomicAdd(&psum[n * 4 + i], s);
            else       atomicAdd(&acc[i - 4], s);   // acc[0]=s3, acc[1]=s4
        }
        int a = ri[0][0] + ri[1][0] + ri[2][0] + ri[3][0];
        int b = ri[0][1] + ri[1][1] + ri[2][1] + ri[3][1];
        if (a) atomicAdd(&cnt_pos[n], a);
        if (b) atomicAdd(&cnt_neg[n], b);
    }
    int* gh = hist1 + n * NB1;
    for (int i = t; i < NB1; i += 256) if (lh[i]) atomicAdd(&gh[i], lh[i]);
}

__global__ void k_sel1(const int* __restrict__ cnt_pos, const int* __restrict__ cnt_neg,
                       const int* __restrict__ hist1,
                       int* __restrict__ mode, int* __restrict__ b1, int* __restrict__ k1) {
    const int n = blockIdx.x;
    const int pos = cnt_pos[n], neg = cnt_neg[n];
    int k = pos * 3; if (k > neg) k = neg;
    if (pos == 0) { if (!threadIdx.x) mode[n] = 2; return; }
    if (k == 0)   { if (!threadIdx.x) mode[n] = 1; return; }
    if (!threadIdx.x) mode[n] = 0;
    int bin, rank;
    if (wave_find(hist1 + n * NB1, NB1, k, &bin, &rank)) { b1[n] = bin; k1[n] = rank; }
}

// ---------------- pass 2: above-bin sums + bin-b1 candidate compaction ------
__global__ void k_compact(const float* __restrict__ outputs, const float* __restrict__ labels,
                          const float* __restrict__ tmask, const int* __restrict__ mode,
                          const int* __restrict__ b1arr, int* __restrict__ cand_cnt,
                          unsigned* __restrict__ ck, float* __restrict__ cv1, float* __restrict__ cv2,
                          double* __restrict__ asum, int* __restrict__ above_cnt) {
    const int n = blockIdx.y;
    if (mode[n] != 0) return;
    const unsigned b1n = (unsigned)b1arr[n];
    __shared__ double rd[4][2];
    __shared__ int ri[4];
    const int t = threadIdx.x;
    const float4* P  = (const float4*)(outputs + (size_t)n * 2 * HWSZ);
    const float4* Th = (const float4*)(outputs + (size_t)n * 2 * HWSZ + HWSZ);
    const float4* G  = (const float4*)(labels  + (size_t)n * 2 * HWSZ);
    const float4* T  = (const float4*)(tmask   + (size_t)n * HWSZ);
    const int base4 = blockIdx.x * (EPB / 4);
    float a1 = 0.f, a2 = 0.f; int ac = 0;
    for (int j = 0; j < 4; ++j) {
        int i4 = base4 + j * 256 + t;
        float4 p = P[i4], th4 = Th[i4], g = G[i4], m = T[i4];
        const float* pp = (const float*)&p;  const float* tt = (const float*)&th4;
        const float* gg = (const float*)&g;  const float* mm = (const float*)&m;
#pragma unroll
        for (int e = 0; e < 4; ++e) {
            float pv = pp[e], tv = tt[e], gv = gg[e], mv = mm[e];
            bool negB = (gv <= 0.5f) && (mv > 0.5f);
            unsigned key = 0; float b1v = 0.f, b2v = 0.f;
            bool incand = false;
            if (negB) {
                key = fkey(pv);
                unsigned bin = key >> 21;
                if (bin >= b1n) {
                    bce_pair(pv, tv, false, b1v, b2v);
                    if (bin > b1n) { a1 += b1v; a2 += b2v; ac++; }
                    else incand = true;
                }
            }
            unsigned long long mb = __ballot(incand);
            if (incand) {
                int lane = t & 63;
                int leader = __ffsll(mb) - 1;
                int cnt = __popcll(mb);
                int base = 0;
                if (lane == leader) base = atomicAdd(&cand_cnt[n], cnt);
                base = __shfl(base, leader, 64);
                int idx = base + __popcll(mb & ((1ull << lane) - 1ull));
                if (idx < CAP) {
                    ck [n * CAP + idx] = key;
                    cv1[n * CAP + idx] = b1v;
                    cv2[n * CAP + idx] = b2v;
                }
            }
        }
    }
    double v0 = a1, v1 = a2;
    for (int off = 32; off; off >>= 1) {
        v0 += __shfl_down(v0, off, 64);
        v1 += __shfl_down(v1, off, 64);
        ac += __shfl_down(ac, off, 64);
    }
    const int lane = t & 63, wid = t >> 6;
    if (!lane) { rd[wid][0] = v0; rd[wid][1] = v1; ri[wid] = ac; }
    __syncthreads();
    if (!t) {
        atomicAdd(&asum[n * 2 + 0], rd[0][0] + rd[1][0] + rd[2][0] + rd[3][0]);
        atomicAdd(&asum[n * 2 + 1], rd[0][1] + rd[1][1] + rd[2][1] + rd[3][1]);
        int a = ri[0] + ri[1] + ri[2] + ri[3];
        if (a) atomicAdd(&above_cnt[n], a);
    }
}

// ---------------- per-sample finalize ---------------------------------------
__global__ void k_final(const float* __restrict__ outputs, const float* __restrict__ labels,
                        const float* __restrict__ tmask,
                        const int* __restrict__ mode, const int* __restrict__ b1arr,
                        const int* __restrict__ k1arr, const int* __restrict__ cnt_pos,
                        const int* __restrict__ cnt_neg, const int* __restrict__ cand_cnt,
                        const unsigned* __restrict__ ck, const float* __restrict__ cv1,
                        const float* __restrict__ cv2, const double* __restrict__ psum,
                        const double* __restrict__ asum, const int* __restrict__ above_cnt,
                        double* __restrict__ acc) {
    __shared__ unsigned sk[CAP];
    __shared__ float sv1[CAP], sv2[CAP];
    __shared__ int h[NB1];
    __shared__ int sb2, sk2, sb3;
    __shared__ double rd[4][2];
    __shared__ int ri[4];
    const int n = blockIdx.x, t = threadIdx.x;
    const int md = mode[n];
    double add1 = 0.0, add2 = 0.0, addc = 0.0;
    if (md == 2) {
        if (!t) { add1 = psum[n*4+2]; add2 = psum[n*4+3]; addc = (double)cnt_neg[n]; }
    } else if (md == 1) {
        if (!t) { add1 = psum[n*4+0]; add2 = psum[n*4+1]; addc = (double)cnt_pos[n]; }
    } else {
        const int k1 = k1arr[n];
        const unsigned b1n = (unsigned)b1arr[n];
        const int cc = cand_cnt[n];
        float f1 = 0.f, f2 = 0.f; int fc = 0;
        if (cc <= CAP) {
            for (int i = t; i < cc; i += 256) {
                sk[i] = ck[n*CAP+i]; sv1[i] = cv1[n*CAP+i]; sv2[i] = cv2[n*CAP+i];
            }
            for (int i = t; i < NB1; i += 256) h[i] = 0;
            __syncthreads();
            for (int i = t; i < cc; i += 256) atomicAdd(&h[(sk[i] >> 10) & 0x7FFu], 1);
            __syncthreads();
            if (t < 64) { int b, r; if (wave_find(h, NB1, k1, &b, &r)) { sb2 = b; sk2 = r; } }
            __syncthreads();
            const unsigned b2 = (unsigned)sb2; const int k2 = sk2;
            for (int i = t; i < 1024; i += 256) h[i] = 0;
            __syncthreads();
            for (int i = t; i < cc; i += 256)
                if (((sk[i] >> 10) & 0x7FFu) == b2) atomicAdd(&h[sk[i] & 0x3FFu], 1);
            __syncthreads();
            if (t < 64) { int b, r; if (wave_find(h, 1024, k2, &b, &r)) sb3 = b; }
            __syncthreads();
            const unsigned thr_key = (b1n << 21) | (b2 << 10) | (unsigned)sb3;
            for (int i = t; i < cc; i += 256)
                if (sk[i] >= thr_key) { f1 += sv1[i]; f2 += sv2[i]; fc++; }
        } else {
            // slow path: full per-sample rescan (general-correctness insurance)
            const float* Pp  = outputs + (size_t)n * 2 * HWSZ;
            const float* Thp = Pp + HWSZ;
            const float* Gp  = labels + (size_t)n * 2 * HWSZ;
            const float* Tp  = tmask + (size_t)n * HWSZ;
            for (int i = t; i < NB1; i += 256) h[i] = 0;
            __syncthreads();
            for (int i = t; i < HWSZ; i += 256) {
                float pv = Pp[i], gv = Gp[i], mv = Tp[i];
                if (gv <= 0.5f && mv > 0.5f) {
                    unsigned key = fkey(pv);
                    if ((key >> 21) == b1n) atomicAdd(&h[(key >> 10) & 0x7FFu], 1);
                }
            }
            __syncthreads();
            if (t < 64) { int b, r; if (wave_find(h, NB1, k1, &b, &r)) { sb2 = b; sk2 = r; } }
            __syncthreads();
            const unsigned b2 = (unsigned)sb2; const int k2 = sk2;
            for (int i = t; i < 1024; i += 256) h[i] = 0;
            __syncthreads();
            for (int i = t; i < HWSZ; i += 256) {
                float pv = Pp[i], gv = Gp[i], mv = Tp[i];
                if (gv <= 0.5f && mv > 0.5f) {
                    unsigned key = fkey(pv);
                    if ((key >> 21) == b1n && ((key >> 10) & 0x7FFu) == b2)
                        atomicAdd(&h[key & 0x3FFu], 1);
                }
            }
            __syncthreads();
            if (t < 64) { int b, r; if (wave_find(h, 1024, k2, &b, &r)) sb3 = b; }
            __syncthreads();
            const unsigned thr_key = (b1n << 21) | (b2 << 10) | (unsigned)sb3;
            for (int i = t; i < HWSZ; i += 256) {
                float pv = Pp[i], gv = Gp[i], mv = Tp[i];
                if (gv <= 0.5f && mv > 0.5f) {
                    unsigned key = fkey(pv);
                    if ((key >> 21) == b1n && key >= thr_key) {
                        float b1v, b2v; bce_pair(pv, Thp[i], false, b1v, b2v);
                        f1 += b1v; f2 += b2v; fc++;
                    }
                }
            }
        }
        // block-reduce partials
        double v0 = f1, v1 = f2;
        for (int off = 32; off; off >>= 1) {
            v0 += __shfl_down(v0, off, 64);
            v1 += __shfl_down(v1, off, 64);
            fc += __shfl_down(fc, off, 64);
        }
        const int lane = t & 63, wid = t >> 6;
        if (!lane) { rd[wid][0] = v0; rd[wid][1] = v1; ri[wid] = fc; }
        __syncthreads();
        if (!t) {
            double pb1 = rd[0][0] + rd[1][0] + rd[2][0] + rd[3][0];
            double pb2 = rd[0][1] + rd[1][1] + rd[2][1] + rd[3][1];
            int pcnt = ri[0] + ri[1] + ri[2] + ri[3];
            add1 = psum[n*4+0] + asum[n*2+0] + pb1;
            add2 = psum[n*4+1] + asum[n*2+1] + pb2;
            addc = (double)cnt_pos[n] + (double)above_cnt[n] + (double)pcnt;
        }
    }
    if (!t) {
        atomicAdd(&acc[2], add1);
        atomicAdd(&acc[3], add2);
        atomicAdd(&acc[4], addc);
    }
}

__global__ void k_fin(const double* __restrict__ acc, float* __restrict__ out) {
    if (threadIdx.x != 0 || blockIdx.x != 0) return;
    double msum = acc[4];
    double lp = (msum > 0.0) ? acc[2] / msum : 0.0;
    double lb = (msum > 0.0) ? acc[3] / msum : 0.0;
    double lt = acc[0] / (acc[1] + 1e-6);
    out[0] = (float)(lp + lb + 10.0 * lt);
    out[1] = (float)lp;
    out[2] = (float)lb;
    out[3] = (float)lt;
}

extern "C" void kernel_launch(void* const* d_in, const int* in_sizes, int n_in,
                              void* d_out, int out_size, void* d_ws, size_t ws_size,
                              hipStream_t stream) {
    const float* outputs = (const float*)d_in[0];
    const float* labels  = (const float*)d_in[1];
    const float* tmask   = (const float*)d_in[2];
    const float* gd      = (const float*)d_in[3];
    float* out = (float*)d_out;

    char* ws = (char*)d_ws;
    double* acc  = (double*)ws;                 // 8 doubles: s3,s4,bce1,bce2,selcnt,...
    double* psum = acc + 8;                     // NS*4: pos1,pos2,neg1,neg2
    double* asum = psum + NS * 4;               // NS*2: above1,above2
    int* cnt_pos   = (int*)(asum + NS * 2);     // NS
    int* cnt_neg   = cnt_pos + NS;
    int* mode      = cnt_neg + NS;
    int* b1        = mode + NS;
    int* k1        = b1 + NS;
    int* cand_cnt  = k1 + NS;
    int* above_cnt = cand_cnt + NS;
    int* hist1     = above_cnt + NS;            // NS*NB1
    unsigned* ck   = (unsigned*)(hist1 + NS * NB1);  // NS*CAP
    float* cv1     = (float*)(ck + NS * CAP);
    float* cv2     = cv1 + NS * CAP;
    (void)cv2; (void)ws_size;
    size_t zbytes = (size_t)((char*)ck - ws);   // cand arrays need no zeroing

    hipMemsetAsync(d_ws, 0, zbytes, stream);

    dim3 g1(BPS, NS), b256(256);
    k_scan1<<<g1, b256, 0, stream>>>(outputs, labels, tmask, gd, hist1, cnt_pos, cnt_neg, psum, acc);
    k_sel1<<<NS, 64, 0, stream>>>(cnt_pos, cnt_neg, hist1, mode, b1, k1);
    k_compact<<<g1, b256, 0, stream>>>(outputs, labels, tmask, mode, b1, cand_cnt, ck, cv1, cv2, asum, above_cnt);
    k_final<<<NS, 256, 0, stream>>>(outputs, labels, tmask, mode, b1, k1, cnt_pos, cnt_neg,
                                    cand_cnt, ck, cv1, cv2, psum, asum, above_cnt, acc);
    k_fin<<<1, 64, 0, stream>>>(acc, out);
}